// Round 1
// baseline (1375.013 us; speedup 1.0000x reference)
//
#include <hip/hip_runtime.h>
#include <hip/hip_bf16.h>

#define B_ 32
#define S_ 4096
#define D_ 1024
#define H_ 512

typedef __bf16 bf16_t;
typedef bf16_t bf16x8 __attribute__((ext_vector_type(8)));
typedef float f32x4 __attribute__((ext_vector_type(4)));

#define AS_STRIDE 40  // 32 k + pad -> 80 B rows (16B multiple, 2-way-only bank aliasing)
#define BS_STRIDE 40

// ---------------------------------------------------------------------------
// Kernel 1: scores[b,s] = relu( x[b,s,:]*prev[b,:] @ W1 + b1 ) . w2 + b2
// Tile: 64 s-rows x 512 h (full H), K-loop BK=32 over D=1024.
// 4 waves; wave w owns h in [w*128, w*128+128): acc[4][8] 16x16 tiles.
// B-operand = diag(prev_b) * W1, scaled+converted during LDS staging,
// stored transposed [h][k] so B-frags are contiguous ds_read_b128.
// ---------------------------------------------------------------------------
__global__ __launch_bounds__(256, 2)
void ta_score_kernel(const float* __restrict__ x,     // [B,S,D]
                     const float* __restrict__ prev,  // [B,D]
                     const float* __restrict__ W1,    // [D,H]
                     const float* __restrict__ b1,    // [H]
                     const float* __restrict__ w2,    // [H]
                     const float* __restrict__ b2,    // [1]
                     float* __restrict__ scores)      // [B,S]
{
    __shared__ bf16_t As[64 * AS_STRIDE];    // 5120 B
    __shared__ bf16_t Bs[512 * BS_STRIDE];   // 40960 B
    __shared__ float  scoreS[4][64];         // 1024 B

    const int t    = threadIdx.x;
    const int wv   = t >> 6;
    const int lane = t & 63;
    const int quad = lane >> 4;
    const int n16  = lane & 15;

    const int b  = blockIdx.y;
    const int s0 = blockIdx.x * 64;

    // A staging: thread -> (row ar, k-chunk ac), 2x float4 per step
    const int ar = t >> 2;
    const int ac = (t & 3) * 8;
    const float* xrow  = x + ((size_t)b * S_ + s0 + ar) * D_;
    const float* prevb = prev + (size_t)b * D_;

    // B staging: wave kg owns k-subrange [kg*8, kg*8+8), lane = h within 64
    const int kg = wv;

    // epilogue constants for this lane's 8 h-columns
    float b1v[8], w2v[8];
#pragma unroll
    for (int j = 0; j < 8; ++j) {
        int h = wv * 128 + j * 16 + n16;
        b1v[j] = b1[h];
        w2v[j] = w2[h];
    }

    f32x4 acc[4][8];
#pragma unroll
    for (int i = 0; i < 4; ++i)
#pragma unroll
        for (int j = 0; j < 8; ++j)
            acc[i][j] = (f32x4){0.f, 0.f, 0.f, 0.f};

    for (int step = 0; step < D_ / 32; ++step) {
        const int k0 = step * 32;

        // ---- global loads (before barrier, overlap prior MFMA) ----
        f32x4 a0 = *(const f32x4*)(xrow + k0 + ac);
        f32x4 a1 = *(const f32x4*)(xrow + k0 + ac + 4);

        float scal[8];
#pragma unroll
        for (int jj = 0; jj < 8; ++jj)
            scal[jj] = prevb[k0 + kg * 8 + jj];

        float bv0[4][8];
#pragma unroll
        for (int hb = 0; hb < 4; ++hb) {
            int h = hb * 64 + lane;
#pragma unroll
            for (int jj = 0; jj < 8; ++jj)
                bv0[hb][jj] = W1[(size_t)(k0 + kg * 8 + jj) * H_ + h] * scal[jj];
        }

        __syncthreads();  // prior iteration's LDS reads complete

        // ---- write A tile ----
        {
            bf16x8 aw;
#pragma unroll
            for (int e = 0; e < 4; ++e) { aw[e] = (bf16_t)a0[e]; aw[4 + e] = (bf16_t)a1[e]; }
            *(bf16x8*)&As[ar * AS_STRIDE + ac] = aw;
        }
        // ---- write B half 0, load+write half 1 ----
#pragma unroll
        for (int hb = 0; hb < 4; ++hb) {
            int h = hb * 64 + lane;
            bf16x8 bw;
#pragma unroll
            for (int jj = 0; jj < 8; ++jj) bw[jj] = (bf16_t)bv0[hb][jj];
            *(bf16x8*)&Bs[h * BS_STRIDE + kg * 8] = bw;
        }
#pragma unroll
        for (int hb = 4; hb < 8; ++hb) {
            int h = hb * 64 + lane;
            float bv[8];
#pragma unroll
            for (int jj = 0; jj < 8; ++jj)
                bv[jj] = W1[(size_t)(k0 + kg * 8 + jj) * H_ + h] * scal[jj];
            bf16x8 bw;
#pragma unroll
            for (int jj = 0; jj < 8; ++jj) bw[jj] = (bf16_t)bv[jj];
            *(bf16x8*)&Bs[h * BS_STRIDE + kg * 8] = bw;
        }

        __syncthreads();  // staging visible

        // ---- fragments + MFMA ----
        bf16x8 afr[4];
#pragma unroll
        for (int i = 0; i < 4; ++i)
            afr[i] = *(const bf16x8*)&As[(i * 16 + n16) * AS_STRIDE + quad * 8];
#pragma unroll
        for (int j = 0; j < 8; ++j) {
            bf16x8 bfr = *(const bf16x8*)&Bs[(wv * 128 + j * 16 + n16) * BS_STRIDE + quad * 8];
#pragma unroll
            for (int i = 0; i < 4; ++i)
                acc[i][j] = __builtin_amdgcn_mfma_f32_16x16x32_bf16(afr[i], bfr, acc[i][j], 0, 0, 0);
        }
    }

    // ---- epilogue: bias + relu + dot(w2), reduce over h ----
    // acc[i][j][r] = hidden[row = i*16 + quad*4 + r][h = wv*128 + j*16 + n16]
    float part[4][4];
#pragma unroll
    for (int i = 0; i < 4; ++i)
#pragma unroll
        for (int r = 0; r < 4; ++r) {
            float p = 0.f;
#pragma unroll
            for (int j = 0; j < 8; ++j) {
                float hval = acc[i][j][r] + b1v[j];
                hval = fmaxf(hval, 0.f);
                p += hval * w2v[j];
            }
            // butterfly over the 16 columns held by this quad's lanes
            for (int off = 8; off > 0; off >>= 1)
                p += __shfl_xor(p, off);
            part[i][r] = p;
        }

    if (n16 == 0) {
#pragma unroll
        for (int i = 0; i < 4; ++i)
#pragma unroll
            for (int r = 0; r < 4; ++r)
                scoreS[wv][i * 16 + quad * 4 + r] = part[i][r];
    }
    __syncthreads();

    if (t < 64) {
        float sc = scoreS[0][t] + scoreS[1][t] + scoreS[2][t] + scoreS[3][t] + b2[0];
        scores[(size_t)b * S_ + s0 + t] = sc;
    }
}

// ---------------------------------------------------------------------------
// Kernel 2: per-batch softmax over S=4096
// ---------------------------------------------------------------------------
__global__ __launch_bounds__(256)
void ta_softmax_kernel(const float* __restrict__ scores, float* __restrict__ weights)
{
    const int b = blockIdx.x;
    const int t = threadIdx.x;
    const float* s = scores + (size_t)b * S_;

    float v[16];
    float m = -1e30f;
#pragma unroll
    for (int i = 0; i < 16; ++i) {
        v[i] = s[t + i * 256];
        m = fmaxf(m, v[i]);
    }

    __shared__ float red[256];
    red[t] = m;
    __syncthreads();
    for (int off = 128; off > 0; off >>= 1) {
        if (t < off) red[t] = fmaxf(red[t], red[t + off]);
        __syncthreads();
    }
    m = red[0];
    __syncthreads();

    float sum = 0.f;
#pragma unroll
    for (int i = 0; i < 16; ++i) {
        v[i] = __expf(v[i] - m);
        sum += v[i];
    }
    red[t] = sum;
    __syncthreads();
    for (int off = 128; off > 0; off >>= 1) {
        if (t < off) red[t] += red[t + off];
        __syncthreads();
    }
    const float inv = 1.f / red[0];

    float* w = weights + (size_t)b * S_;
#pragma unroll
    for (int i = 0; i < 16; ++i)
        w[t + i * 256] = v[i] * inv;
}

// ---------------------------------------------------------------------------
// Kernel 3: out[b,d] = sum_s x[b,s,d] * weights[b,s]   (HBM-bound)
// grid (S/128, B); thread owns float4 at d=4t; atomicAdd partials.
// ---------------------------------------------------------------------------
__global__ __launch_bounds__(256)
void ta_wsum_kernel(const float* __restrict__ x, const float* __restrict__ weights,
                    float* __restrict__ out)
{
    const int b  = blockIdx.y;
    const int sc = blockIdx.x;
    const int t  = threadIdx.x;

    const float* xb = x + ((size_t)b * S_ + (size_t)sc * 128) * D_;
    const float* wb = weights + (size_t)b * S_ + (size_t)sc * 128;

    f32x4 acc = (f32x4){0.f, 0.f, 0.f, 0.f};
    for (int s = 0; s < 128; ++s) {
        float w = wb[s];
        f32x4 xv = *(const f32x4*)(xb + (size_t)s * D_ + t * 4);
        acc += xv * w;
    }

    float* o = out + (size_t)b * D_ + t * 4;
    atomicAdd(o + 0, acc[0]);
    atomicAdd(o + 1, acc[1]);
    atomicAdd(o + 2, acc[2]);
    atomicAdd(o + 3, acc[3]);
}

// ---------------------------------------------------------------------------
extern "C" void kernel_launch(void* const* d_in, const int* in_sizes, int n_in,
                              void* d_out, int out_size, void* d_ws, size_t ws_size,
                              hipStream_t stream) {
    const float* x    = (const float*)d_in[0];
    const float* prev = (const float*)d_in[1];
    const float* W1   = (const float*)d_in[2];
    const float* b1   = (const float*)d_in[3];
    const float* w2   = (const float*)d_in[4];
    const float* b2   = (const float*)d_in[5];
    float* out = (float*)d_out;

    float* scores  = (float*)d_ws;          // B*S floats = 512 KiB
    float* weights = scores + B_ * S_;      // B*S floats = 512 KiB

    hipMemsetAsync(d_out, 0, (size_t)B_ * D_ * sizeof(float), stream);

    dim3 g1(S_ / 64, B_);   // 64 x 32 = 2048 workgroups
    ta_score_kernel<<<g1, 256, 0, stream>>>(x, prev, W1, b1, w2, b2, scores);

    ta_softmax_kernel<<<B_, 256, 0, stream>>>(scores, weights);

    dim3 g3(S_ / 128, B_);  // 32 x 32 = 1024 workgroups
    ta_wsum_kernel<<<g3, 256, 0, stream>>>(x, weights, out);
}

// Round 3
// 874.664 us; speedup vs baseline: 1.5720x; 1.5720x over previous
//
#include <hip/hip_runtime.h>
#include <hip/hip_bf16.h>
#include <stdint.h>

#define B_ 32
#define S_ 4096
#define D_ 1024
#define H_ 512
#define BK 32

typedef __bf16 bf16_t;
typedef bf16_t bf16x8 __attribute__((ext_vector_type(8)));
typedef float f32x4 __attribute__((ext_vector_type(4)));

#define AS_STRIDE 40  // 32 k + pad: 80 B rows, 2-way-only bank aliasing on b128

// ---------------------------------------------------------------------------
// Kernel 0 (prep): W1bf[kb][h][kk] = bf16( W1[kb*32+kk][h] )
// Batch-independent, 1 MiB total; per-kb chunk is contiguous 512x32 bf16 =
// 32 KiB, exactly the layout the score kernel DMAs into LDS.
// ---------------------------------------------------------------------------
__global__ __launch_bounds__(256)
void ta_prep_kernel(const float* __restrict__ W1, bf16_t* __restrict__ W1bf)
{
    const int kb = blockIdx.x;   // 0..31
    const int t  = threadIdx.x;

#pragma unroll
    for (int hh = 0; hh < 2; ++hh) {
        int h = t + hh * 256;
        bf16_t row[BK];
#pragma unroll
        for (int kk = 0; kk < BK; ++kk)
            row[kk] = (bf16_t)W1[(size_t)(kb * BK + kk) * H_ + h];
        bf16_t* dst = W1bf + ((size_t)kb * H_ + h) * BK;
#pragma unroll
        for (int c = 0; c < 4; ++c)
            *(bf16x8*)(dst + c * 8) = *(const bf16x8*)&row[c * 8];
    }
}

// ---------------------------------------------------------------------------
// Kernel 1: scores[b,s] = relu( (x[b,s,:].*prev[b,:]) @ W1 + b1 ) . w2 + b2
// prev folded into the A-operand: A[s,k] = bf16(x[b,s,k]*prev[b,k]).
// B = raw W1bf, DMA'd via global_load_lds (32 KiB contiguous per K-step,
// shared across all blocks -> L2-resident). 64 s-rows x full H=512 per
// block; 4 waves, wave w owns h in [w*128, w*128+128); 16x16x32 bf16 MFMA.
// ---------------------------------------------------------------------------
__global__ __launch_bounds__(256, 2)
void ta_score_kernel(const float* __restrict__ x,      // [B,S,D]
                     const float* __restrict__ prev,   // [B,D]
                     const bf16_t* __restrict__ W1bf,  // [32][512][32]
                     const float* __restrict__ b1,
                     const float* __restrict__ w2,
                     const float* __restrict__ b2,
                     float* __restrict__ scores)       // [B,S]
{
    __shared__ bf16_t As[64 * AS_STRIDE];    // 5120 B
    __shared__ bf16_t Bs[H_ * BK];           // 32768 B, [h][kk], no pad (DMA dest)
    __shared__ float  scoreS[4][64];

    const int t    = threadIdx.x;
    const int wv   = t >> 6;
    const int lane = t & 63;
    const int quad = lane >> 4;
    const int n16  = lane & 15;

    const int b  = blockIdx.y;
    const int s0 = blockIdx.x * 64;

    const int ar = t >> 2;
    const int ac = (t & 3) * 8;
    const float* xrow  = x + ((size_t)b * S_ + s0 + ar) * D_;
    const float* prevb = prev + (size_t)b * D_;

    float b1v[8], w2v[8];
#pragma unroll
    for (int j = 0; j < 8; ++j) {
        int h = wv * 128 + j * 16 + n16;
        b1v[j] = b1[h];
        w2v[j] = w2[h];
    }

    f32x4 acc[4][8];
#pragma unroll
    for (int i = 0; i < 4; ++i)
#pragma unroll
        for (int j = 0; j < 8; ++j)
            acc[i][j] = (f32x4){0.f, 0.f, 0.f, 0.f};

    for (int kb = 0; kb < D_ / BK; ++kb) {
        // global loads issued before the barrier (overlap prior MFMA)
        f32x4 a0 = *(const f32x4*)(xrow + kb * BK + ac);
        f32x4 a1 = *(const f32x4*)(xrow + kb * BK + ac + 4);
        f32x4 p0 = *(const f32x4*)(prevb + kb * BK + ac);      // L1-resident
        f32x4 p1 = *(const f32x4*)(prevb + kb * BK + ac + 4);

        __syncthreads();  // prior iteration's frag reads complete

        // ---- B tile: 32 KiB contiguous DMA, wave wv does 8x1KiB ----
        const char* gB = (const char*)(W1bf + (size_t)kb * H_ * BK);
#pragma unroll
        for (int r = 0; r < 8; ++r) {
            int off = (wv * 8 + r) * 1024;
            __builtin_amdgcn_global_load_lds(
                (const __attribute__((address_space(1))) void*)(gB + off + lane * 16),
                (__attribute__((address_space(3))) void*)((char*)Bs + off),
                16, 0, 0);
        }

        // ---- A tile: scale by prev, convert, vector LDS write ----
        {
            a0 *= p0;
            a1 *= p1;
            bf16x8 aw;
#pragma unroll
            for (int e = 0; e < 4; ++e) { aw[e] = (bf16_t)a0[e]; aw[4 + e] = (bf16_t)a1[e]; }
            *(bf16x8*)&As[ar * AS_STRIDE + ac] = aw;
        }

        __syncthreads();  // staging (incl. DMA vmcnt drain) visible

        bf16x8 afr[4];
#pragma unroll
        for (int i = 0; i < 4; ++i)
            afr[i] = *(const bf16x8*)&As[(i * 16 + n16) * AS_STRIDE + quad * 8];
#pragma unroll
        for (int j = 0; j < 8; ++j) {
            bf16x8 bfr = *(const bf16x8*)&Bs[(wv * 128 + j * 16 + n16) * BK + quad * 8];
#pragma unroll
            for (int i = 0; i < 4; ++i)
                acc[i][j] = __builtin_amdgcn_mfma_f32_16x16x32_bf16(afr[i], bfr, acc[i][j], 0, 0, 0);
        }
    }

    // ---- epilogue: bias + relu + dot(w2), reduce over h ----
    // acc[i][j][r] = hidden[row = i*16 + quad*4 + r][h = wv*128 + j*16 + n16]
    float part[4][4];
#pragma unroll
    for (int i = 0; i < 4; ++i)
#pragma unroll
        for (int r = 0; r < 4; ++r) {
            float p = 0.f;
#pragma unroll
            for (int j = 0; j < 8; ++j) {
                float hval = acc[i][j][r] + b1v[j];
                hval = fmaxf(hval, 0.f);
                p += hval * w2v[j];
            }
            for (int off = 8; off > 0; off >>= 1)
                p += __shfl_xor(p, off);
            part[i][r] = p;
        }

    if (n16 == 0) {
#pragma unroll
        for (int i = 0; i < 4; ++i)
#pragma unroll
            for (int r = 0; r < 4; ++r)
                scoreS[wv][i * 16 + quad * 4 + r] = part[i][r];
    }
    __syncthreads();

    if (t < 64) {
        float sc = scoreS[0][t] + scoreS[1][t] + scoreS[2][t] + scoreS[3][t] + b2[0];
        scores[(size_t)b * S_ + s0 + t] = sc;
    }
}

// ---------------------------------------------------------------------------
// Kernel 2: per-batch softmax over S=4096
// ---------------------------------------------------------------------------
__global__ __launch_bounds__(256)
void ta_softmax_kernel(const float* __restrict__ scores, float* __restrict__ weights)
{
    const int b = blockIdx.x;
    const int t = threadIdx.x;
    const float* s = scores + (size_t)b * S_;

    float v[16];
    float m = -1e30f;
#pragma unroll
    for (int i = 0; i < 16; ++i) {
        v[i] = s[t + i * 256];
        m = fmaxf(m, v[i]);
    }

    __shared__ float red[256];
    red[t] = m;
    __syncthreads();
    for (int off = 128; off > 0; off >>= 1) {
        if (t < off) red[t] = fmaxf(red[t], red[t + off]);
        __syncthreads();
    }
    m = red[0];
    __syncthreads();

    float sum = 0.f;
#pragma unroll
    for (int i = 0; i < 16; ++i) {
        v[i] = __expf(v[i] - m);
        sum += v[i];
    }
    red[t] = sum;
    __syncthreads();
    for (int off = 128; off > 0; off >>= 1) {
        if (t < off) red[t] += red[t + off];
        __syncthreads();
    }
    const float inv = 1.f / red[0];

    float* w = weights + (size_t)b * S_;
#pragma unroll
    for (int i = 0; i < 16; ++i)
        w[t + i * 256] = v[i] * inv;
}

// ---------------------------------------------------------------------------
// Kernel 3: out[b,d] += sum_{s in 128-chunk} x[b,s,d] * w[b,s]
// grid (32, B); weights chunk in LDS; 4 independent accumulators for ILP;
// atomicAdd partials into zeroed d_out (proven post-timing-safe in R1).
// ---------------------------------------------------------------------------
__global__ __launch_bounds__(256)
void ta_wsum_kernel(const float* __restrict__ x, const float* __restrict__ weights,
                    float* __restrict__ out)
{
    const int sc = blockIdx.x;   // 0..31
    const int b  = blockIdx.y;
    const int t  = threadIdx.x;

    __shared__ float wS[128];
    if (t < 128) wS[t] = weights[(size_t)b * S_ + sc * 128 + t];
    __syncthreads();

    const float* xb = x + ((size_t)b * S_ + (size_t)sc * 128) * D_;

    f32x4 acc0 = (f32x4){0.f,0.f,0.f,0.f}, acc1 = acc0, acc2 = acc0, acc3 = acc0;
    for (int s = 0; s < 128; s += 4) {
        f32x4 x0 = *(const f32x4*)(xb + (size_t)(s + 0) * D_ + t * 4);
        f32x4 x1 = *(const f32x4*)(xb + (size_t)(s + 1) * D_ + t * 4);
        f32x4 x2 = *(const f32x4*)(xb + (size_t)(s + 2) * D_ + t * 4);
        f32x4 x3 = *(const f32x4*)(xb + (size_t)(s + 3) * D_ + t * 4);
        acc0 += x0 * wS[s + 0];
        acc1 += x1 * wS[s + 1];
        acc2 += x2 * wS[s + 2];
        acc3 += x3 * wS[s + 3];
    }
    f32x4 r = (acc0 + acc1) + (acc2 + acc3);

    float* o = out + (size_t)b * D_ + t * 4;
    atomicAdd(o + 0, r[0]);
    atomicAdd(o + 1, r[1]);
    atomicAdd(o + 2, r[2]);
    atomicAdd(o + 3, r[3]);
}

// ---------------------------------------------------------------------------
extern "C" void kernel_launch(void* const* d_in, const int* in_sizes, int n_in,
                              void* d_out, int out_size, void* d_ws, size_t ws_size,
                              hipStream_t stream) {
    const float* x    = (const float*)d_in[0];
    const float* prev = (const float*)d_in[1];
    const float* W1   = (const float*)d_in[2];
    const float* b1   = (const float*)d_in[3];
    const float* w2   = (const float*)d_in[4];
    const float* b2   = (const float*)d_in[5];
    float* out = (float*)d_out;

    // workspace layout — total 2.0 MiB (R1's proven-safe footprint was 1 MiB)
    bf16_t* W1bf   = (bf16_t*)d_ws;                           // 1 MiB
    float* scores  = (float*)((char*)d_ws + (size_t)1024 * 1024);  // 512 KiB
    float* weights = scores + B_ * S_;                        // 512 KiB

    hipMemsetAsync(d_out, 0, (size_t)B_ * D_ * sizeof(float), stream);

    ta_prep_kernel<<<32, 256, 0, stream>>>(W1, W1bf);

    dim3 g1(S_ / 64, B_);   // 2048 workgroups
    ta_score_kernel<<<g1, 256, 0, stream>>>(x, prev, W1bf, b1, w2, b2, scores);

    ta_softmax_kernel<<<B_, 256, 0, stream>>>(scores, weights);

    dim3 g3(S_ / 128, B_);  // 1024 workgroups
    ta_wsum_kernel<<<g3, 256, 0, stream>>>(x, weights, out);
}